// Round 16
// baseline (1740.162 us; speedup 1.0000x reference)
//
#include <hip/hip_runtime.h>

#define N_X  40000
#define NN   50000
#define NE   800000
#define MPAD 50048

using short8  = __attribute__((ext_vector_type(8))) short;
using floatx4 = __attribute__((ext_vector_type(4))) float;
using uintx2  = __attribute__((ext_vector_type(2))) unsigned int;
using uintx4  = __attribute__((ext_vector_type(4))) unsigned int;

typedef const __attribute__((address_space(1))) void gv_t;
typedef __attribute__((address_space(3))) void lv_t;

__device__ __forceinline__ unsigned short f2bf(float f) {
  unsigned u = __float_as_uint(f);
  u += 0x7FFF + ((u >> 16) & 1);           // RNE
  return (unsigned short)(u >> 16);
}
__device__ __forceinline__ float bf2f(unsigned v) {
  return __uint_as_float(v << 16);
}
__device__ __forceinline__ float h2f(unsigned v) {
  unsigned short s = (unsigned short)v;
  _Float16 f;
  __builtin_memcpy(&f, &s, 2);
  return (float)f;
}
__device__ __forceinline__ unsigned short f2h(float f) {
  _Float16 h = (_Float16)f;
  unsigned short s;
  __builtin_memcpy(&s, &h, 2);
  return s;
}

// ---------------- preprocessing ----------------
__global__ void k_deg(const int* __restrict__ dst, int* __restrict__ deg) {
  int e = blockIdx.x * blockDim.x + threadIdx.x;
  if (e < NE) atomicAdd(&deg[dst[e]], 1);
}

__global__ void k_dis(const int* __restrict__ deg, float* __restrict__ dis) {
  int i = blockIdx.x * blockDim.x + threadIdx.x;
  if (i < NN) dis[i] = deg[i] > 0 ? rsqrtf((float)deg[i]) : 0.f;
}

#define SCAN_B 1024
#define SCAN_NB 49
__global__ void k_scan1(const int* __restrict__ deg, int* __restrict__ rowp,
                        int* __restrict__ bsum) {
  __shared__ int buf[SCAN_B];
  int b = blockIdx.x;
  int i = b * SCAN_B + threadIdx.x;
  int v = (i < NN) ? deg[i] : 0;
  buf[threadIdx.x] = v;
  __syncthreads();
  for (int off = 1; off < SCAN_B; off <<= 1) {
    int t = (threadIdx.x >= off) ? buf[threadIdx.x - off] : 0;
    __syncthreads();
    buf[threadIdx.x] += t;
    __syncthreads();
  }
  if (i < NN) rowp[i] = buf[threadIdx.x] - v;   // block-local exclusive
  if (threadIdx.x == SCAN_B - 1) bsum[b] = buf[SCAN_B - 1];
}

__global__ void k_scan2(int* __restrict__ bsum) {
  if (threadIdx.x == 0) {
    int acc = 0;
    for (int i = 0; i < SCAN_NB; ++i) { int t = bsum[i]; bsum[i] = acc; acc += t; }
  }
}

__global__ void k_scan3(int* __restrict__ rowp, const int* __restrict__ bsum) {
  int i = blockIdx.x * blockDim.x + threadIdx.x;
  if (i < NN) rowp[i] += bsum[i >> 10];
  if (i == 0) rowp[NN] = NE;
}

__global__ void k_build(const int* __restrict__ dst, const int* __restrict__ src,
                        const int* __restrict__ typ, const float* __restrict__ dis,
                        const int* __restrict__ rowp, int* __restrict__ cur,
                        uintx2* __restrict__ ed) {
  int e = blockIdx.x * blockDim.x + threadIdx.x;
  if (e >= NE) return;
  int d = dst[e], s = src[e];
  int p = rowp[d] + atomicAdd(&cur[d], 1);
  uintx2 v;
  v.x = (unsigned)s | ((unsigned)typ[e] << 28);
  v.y = __float_as_uint(dis[d] * dis[s]);
  ed[p] = v;
}

// ---------------- per-layer kernels ----------------
// layer 0: concat(x, emb) -> Gh/Gl [NN][128]
__global__ void k_prep0(const float* __restrict__ x, const float* __restrict__ emb,
                        unsigned short* __restrict__ Gh, unsigned short* __restrict__ Gl) {
  int idx = blockIdx.x * blockDim.x + threadIdx.x;
  if (idx >= NN * 32) return;
  int r = idx >> 5;
  const float* srcp = (r < N_X) ? (x + (size_t)idx * 4)
                                : (emb + ((size_t)idx - (size_t)N_X * 32) * 4);
  float4 hv = *(const float4*)srcp;
  float vv[4] = {hv.x, hv.y, hv.z, hv.w};
  unsigned hw[2], lw[2];
#pragma unroll
  for (int q = 0; q < 2; ++q) {
    unsigned short h0 = f2bf(vv[2 * q]), h1 = f2bf(vv[2 * q + 1]);
    unsigned short l0 = f2bf(vv[2 * q] - bf2f(h0)), l1 = f2bf(vv[2 * q + 1] - bf2f(h1));
    hw[q] = (unsigned)h0 | ((unsigned)h1 << 16);
    lw[q] = (unsigned)l0 | ((unsigned)l1 << 16);
  }
  size_t o = (size_t)idx * 4;
  *(uintx2*)(Gh + o) = uintx2{hw[0], hw[1]};
  *(uintx2*)(Gl + o) = uintx2{lw[0], lw[1]};
}

// BN (inline scale/shift from raw sums) + ReLU: Hb bf16 [NN][din] -> Gh/Gl.
__global__ void k_prep(const unsigned short* __restrict__ Hb,
                       const float* __restrict__ bns, const float* __restrict__ g,
                       const float* __restrict__ b, unsigned short* __restrict__ Gh,
                       unsigned short* __restrict__ Gl, int din) {
  int idx = blockIdx.x * blockDim.x + threadIdx.x;
  if (idx >= NN * (din >> 3)) return;
  int c8 = (idx & ((din >> 3) - 1)) * 8;
  uintx4 hv = *(const uintx4*)(Hb + (size_t)idx * 8);
  unsigned hwv[4] = {hv.x, hv.y, hv.z, hv.w};
  unsigned hw[4], lw[4];
#pragma unroll
  for (int q = 0; q < 4; ++q) {
    unsigned short oo[2];
#pragma unroll
    for (int p = 0; p < 2; ++p) {
      int c = c8 + 2 * q + p;
      float mean = bns[c] * (1.f / NN);
      float var = bns[din + c] * (1.f / NN) - mean * mean;
      float rs = rsqrtf(var + 1e-5f);
      float sc = rs * g[c];
      float sh = b[c] - mean * sc;
      float v = bf2f((hwv[q] >> (16 * p)) & 0xFFFFu);
      v = fmaxf(v * sc + sh, 0.f);
      oo[p] = f2bf(v);
      float lo = v - bf2f(oo[p]);
      if (p == 0) lw[q] = (unsigned)f2bf(lo);
      else        lw[q] |= ((unsigned)f2bf(lo) << 16);
    }
    hw[q] = (unsigned)oo[0] | ((unsigned)oo[1] << 16);
  }
  size_t o = (size_t)idx * 8;
  *(uintx4*)(Gh + o) = uintx4{hw[0], hw[1], hw[2], hw[3]};
  *(uintx4*)(Gl + o) = uintx4{lw[0], lw[1], lw[2], lw[3]};
}

// Wc2T[n][k] hi/lo: n in [0,4*dout) columns of [root|W0|W1|W2], k in [0,din)
__global__ void k_wcat2(const float* __restrict__ root, const float* __restrict__ W,
                        unsigned short* __restrict__ BhT, unsigned short* __restrict__ BlT,
                        int din, int dout) {
  int idx = blockIdx.x * blockDim.x + threadIdx.x;
  if (idx >= 4 * dout * din) return;
  int n = idx / din, k = idx % din;
  float v;
  if (n < dout) v = root[(size_t)k * dout + n];
  else {
    int r = n / dout - 1, c = n % dout;
    v = W[((size_t)r * din + k) * dout + c];
  }
  unsigned short h = f2bf(v);
  BhT[idx] = h;
  BlT[idx] = f2bf(v - bf2f(h));
}

// ------ split-f32 MFMA GEMM, 256x128 tile, PHASE-LOCKED 8-wave schedule ------
// m201-template port: 512 threads (8 waves, 2m x 4n), 3-buffer LDS rotation
// (48KB each, 144KB total -> 1 block/CU, 2 waves/SIMD). Per K-tile:
// counted vmcnt(6) + barrier, then 4 quadrant phases each
// {ds_read frags | stage-issue(ph0, into buf (tk+2)%3 - nobody reads it) |
//  barrier | setprio(1) 12 MFMA setprio(0) | barrier}.
// Coalesced global_load_lds w/ XOR-swizzled source + matching swizzled
// ds_read (conflict-free, verified R7). vmcnt never drains mid-loop (T4).
template <int NK>
__global__ __launch_bounds__(512, 1) void k_gemm4(
    const unsigned short* __restrict__ Ah, const unsigned short* __restrict__ Al,
    const unsigned short* __restrict__ Bh, const unsigned short* __restrict__ Bl,
    float* __restrict__ Rroot, unsigned short* __restrict__ P,
    int M, int dout, int ny) {
  constexpr int K = NK * 32;
  constexpr int TC = 48;               // 32 A chunks + 16 B chunks (1KB each)
  constexpr int CPW = 6;               // chunks staged per wave
  __shared__ __align__(16) char lds[3][TC * 1024];

  const int tid = threadIdx.x;
  const int lane = tid & 63;
  const int w = tid >> 6;              // 0..7
  const int wm = w >> 2, wn = w & 3;
  const int r16 = lane & 15, kg = lane >> 4;

  // bijective XCD swizzle (m204); consecutive t share an A-panel (same bm)
  const int nwg = gridDim.x;
  const int q = nwg >> 3, r = nwg & 7;
  const int xcd = blockIdx.x & 7, pos = blockIdx.x >> 3;
  const int t = (xcd < r ? xcd * (q + 1) : r * (q + 1) + (xcd - r) * q) + pos;
  const int bm = (t / ny) * 256;
  const int bn = (t % ny) * 128;

  // coalesced per-lane staging source with XOR-swizzled seg
  const int rowseg = lane >> 2;
  const int seg = (lane & 3) ^ ((lane >> 3) & 3);
  const unsigned short* gb[CPW];
#pragma unroll
  for (int i = 0; i < CPW; ++i) {
    int c = w * CPW + i;
    const unsigned short* base;
    int row0;
    if (c < 16)      { base = Ah; row0 = bm + c * 16; }
    else if (c < 32) { base = Al; row0 = bm + (c - 16) * 16; }
    else if (c < 40) { base = Bh; row0 = bn + (c - 32) * 16; }
    else             { base = Bl; row0 = bn + (c - 40) * 16; }
    gb[i] = base + (size_t)(row0 + rowseg) * K + seg * 8;
  }

  floatx4 acc[8][2];
#pragma unroll
  for (int i = 0; i < 8; ++i)
#pragma unroll
    for (int jj = 0; jj < 2; ++jj) acc[i][jj] = (floatx4)0.f;

  auto stage = [&](int b, int tk) {
#pragma unroll
    for (int i = 0; i < CPW; ++i)
      __builtin_amdgcn_global_load_lds((gv_t*)(gb[i] + tk * 32),
                                       (lv_t*)&lds[b][(w * CPW + i) * 1024],
                                       16, 0, 0);
  };

  stage(0, 0);
  stage(1, 1);

  const int fo = r16 * 64 + ((kg ^ ((r16 >> 1) & 3)) * 16);

#pragma unroll
  for (int tk = 0; tk < NK; ++tk) {
    // tile entry: own 6 staged loads for tile tk retired (tk+1's stay in
    // flight); barrier makes completion collective across waves
    if (tk < NK - 1) asm volatile("s_waitcnt vmcnt(6)" ::: "memory");
    else             asm volatile("s_waitcnt vmcnt(0)" ::: "memory");
    __syncthreads();

    const char* Lb = lds[tk % 3];
    const int sb = (tk + 2) % 3;

#pragma unroll
    for (int ph = 0; ph < 4; ++ph) {
      const int m0 = (ph & 1) * 4;
      const int nt = ph >> 1;
      short8 afh[4], afl[4];
#pragma unroll
      for (int i = 0; i < 4; ++i) {
        afh[i] = *(const short8*)(Lb + (wm * 8 + m0 + i) * 1024 + fo);
        afl[i] = *(const short8*)(Lb + (16 + wm * 8 + m0 + i) * 1024 + fo);
      }
      short8 bfh = *(const short8*)(Lb + (32 + wn * 2 + nt) * 1024 + fo);
      short8 bfl = *(const short8*)(Lb + (40 + wn * 2 + nt) * 1024 + fo);
      if (ph == 0 && tk + 2 < NK) stage(sb, tk + 2);
      __syncthreads();
      __builtin_amdgcn_s_setprio(1);
#pragma unroll
      for (int i = 0; i < 4; ++i) {
        acc[m0 + i][nt] = __builtin_amdgcn_mfma_f32_16x16x32_bf16(afh[i], bfh, acc[m0 + i][nt], 0, 0, 0);
        acc[m0 + i][nt] = __builtin_amdgcn_mfma_f32_16x16x32_bf16(afh[i], bfl, acc[m0 + i][nt], 0, 0, 0);
        acc[m0 + i][nt] = __builtin_amdgcn_mfma_f32_16x16x32_bf16(afl[i], bfh, acc[m0 + i][nt], 0, 0, 0);
      }
      __builtin_amdgcn_s_setprio(0);
      __syncthreads();
    }
  }

  // epilogue: D row = (lane>>4)*4 + reg, col = lane&15
#pragma unroll
  for (int mt = 0; mt < 8; ++mt) {
    const int gr0 = bm + wm * 128 + mt * 16 + kg * 4;
#pragma unroll
    for (int nt = 0; nt < 2; ++nt) {
      const int n0 = bn + wn * 32 + nt * 16;
      const int sec = n0 / dout;       // uniform within 16-col group
      const int colL = n0 - sec * dout + r16;
#pragma unroll
      for (int rr = 0; rr < 4; ++rr) {
        const int gr = gr0 + rr;
        if (gr >= M) continue;
        const float o = acc[mt][nt][rr];
        if (sec == 0) Rroot[(size_t)gr * dout + colL] = o;
        else          P[((size_t)gr * 3 + (sec - 1)) * dout + colL] = f2h(o);
      }
    }
  }
}

// P-space aggregation: ONE WAVE PER NODE (verified R12 structure).
// L lanes per edge, 8 f16 cols per lane. Output: bf16 H (l<7) or f32 (l==7).
template <int L, bool F32OUT>
__global__ void k_agg2(const unsigned short* __restrict__ P,
                       const float* __restrict__ Rroot,
                       const float* __restrict__ bias,
                       const int* __restrict__ rowp, const uintx2* __restrict__ ed,
                       void* __restrict__ OutV) {
  constexpr int G = 64 / L;
  constexpr int dout = L * 8;
  const int wid = (blockIdx.x * 256 + threadIdx.x) >> 6;
  if (wid >= NN) return;
  const int lane = threadIdx.x & 63;
  const int grp = lane / L;
  const int c0 = (lane & (L - 1)) * 8;
  const int beg = rowp[wid], end = rowp[wid + 1];
  float a[8] = {};
  for (int i = beg + grp; i < end; i += G) {
    const uintx2 e = ed[i];
    const float wv = __uint_as_float(e.y);
    const unsigned tt = e.x >> 28;
    const size_t off = ((size_t)(e.x & 0x0FFFFFFFu) * 3 + tt) * dout + c0;
    const uintx4 g = *(const uintx4*)(P + off);
    a[0] += wv * h2f(g.x & 0xFFFFu);
    a[1] += wv * h2f(g.x >> 16);
    a[2] += wv * h2f(g.y & 0xFFFFu);
    a[3] += wv * h2f(g.y >> 16);
    a[4] += wv * h2f(g.z & 0xFFFFu);
    a[5] += wv * h2f(g.z >> 16);
    a[6] += wv * h2f(g.w & 0xFFFFu);
    a[7] += wv * h2f(g.w >> 16);
  }
#pragma unroll
  for (int off = L; off < 64; off <<= 1) {
#pragma unroll
    for (int qq = 0; qq < 8; ++qq) a[qq] += __shfl_xor(a[qq], off);
  }
  if (grp == 0) {
    const size_t ob = (size_t)wid * dout + c0;
    const float4 bv0 = *(const float4*)(bias + c0);
    const float4 bv1 = *(const float4*)(bias + c0 + 4);
    const float4 rv0 = *(const float4*)(Rroot + ob);
    const float4 rv1 = *(const float4*)(Rroot + ob + 4);
    float o[8];
    o[0] = rv0.x + bv0.x + a[0];
    o[1] = rv0.y + bv0.y + a[1];
    o[2] = rv0.z + bv0.z + a[2];
    o[3] = rv0.w + bv0.w + a[3];
    o[4] = rv1.x + bv1.x + a[4];
    o[5] = rv1.y + bv1.y + a[5];
    o[6] = rv1.z + bv1.z + a[6];
    o[7] = rv1.w + bv1.w + a[7];
    if constexpr (F32OUT) {
      float* Out = (float*)OutV;
      *(float4*)(Out + ob) = make_float4(o[0], o[1], o[2], o[3]);
      *(float4*)(Out + ob + 4) = make_float4(o[4], o[5], o[6], o[7]);
    } else {
      unsigned short* Out = (unsigned short*)OutV;
      uintx4 pk;
      pk.x = (unsigned)f2bf(o[0]) | ((unsigned)f2bf(o[1]) << 16);
      pk.y = (unsigned)f2bf(o[2]) | ((unsigned)f2bf(o[3]) << 16);
      pk.z = (unsigned)f2bf(o[4]) | ((unsigned)f2bf(o[5]) << 16);
      pk.w = (unsigned)f2bf(o[6]) | ((unsigned)f2bf(o[7]) << 16);
      *(uintx4*)(Out + ob) = pk;
    }
  }
}

// ---------------- batch-norm stats (bf16 H, vectorized x8) ----------------
__global__ void k_bnstats(const unsigned short* __restrict__ Hb,
                          float* __restrict__ sums, int d) {
  __shared__ float ls[512];            // [sum(0..255) | sumsq(256..511)]
  const int cg = d >> 3;               // col-groups of 8
  const int rpb = 256 / cg;            // rows in flight per block
  const int cgi = threadIdx.x & (cg - 1);
  const int rl = threadIdx.x / cg;
  const int c0 = cgi * 8;
  for (int i = threadIdx.x; i < 512; i += 256) ls[i] = 0.f;
  __syncthreads();

  float s[8] = {}, s2[8] = {};
  for (int row = blockIdx.x * rpb + rl; row < NN; row += gridDim.x * rpb) {
    uintx4 hv = *(const uintx4*)(Hb + (size_t)row * d + c0);
    unsigned wv[4] = {hv.x, hv.y, hv.z, hv.w};
#pragma unroll
    for (int q = 0; q < 4; ++q) {
      float v0 = bf2f(wv[q] & 0xFFFFu);
      float v1 = bf2f(wv[q] >> 16);
      s[2 * q] += v0;  s2[2 * q] += v0 * v0;
      s[2 * q + 1] += v1;  s2[2 * q + 1] += v1 * v1;
    }
  }
#pragma unroll
  for (int q = 0; q < 8; ++q) {
    atomicAdd(&ls[c0 + q], s[q]);
    atomicAdd(&ls[256 + c0 + q], s2[q]);
  }
  __syncthreads();
  if (threadIdx.x < d) {
    atomicAdd(&sums[threadIdx.x], ls[threadIdx.x]);
    atomicAdd(&sums[d + threadIdx.x], ls[256 + threadIdx.x]);
  }
}

// ---------------- host driver ----------------
extern "C" void kernel_launch(void* const* d_in, const int* in_sizes, int n_in,
                              void* d_out, int out_size, void* d_ws, size_t ws_size,
                              hipStream_t stream) {
  const float* x   = (const float*)d_in[0];
  const float* emb = (const float*)d_in[1];
  const float* conv_w[4] = {(const float*)d_in[2], (const float*)d_in[5],
                            (const float*)d_in[8], (const float*)d_in[11]};
  const float* conv_r[4] = {(const float*)d_in[3], (const float*)d_in[6],
                            (const float*)d_in[9], (const float*)d_in[12]};
  const float* conv_b[4] = {(const float*)d_in[4], (const float*)d_in[7],
                            (const float*)d_in[10], (const float*)d_in[13]};
  const float* n1g = (const float*)d_in[14];
  const float* n1b = (const float*)d_in[15];
  const float* n2g = (const float*)d_in[16];
  const float* n2b = (const float*)d_in[17];
  const int* eidx = (const int*)d_in[18];
  const int* etyp = (const int*)d_in[19];
  const int* dst  = eidx;
  const int* srcp = eidx + NE;
  float* out = (float*)d_out;

  char* w = (char*)d_ws;
  auto alloc = [&](size_t bytes) {
    char* p = w;
    w += (bytes + 255) & ~(size_t)255;
    return p;
  };
  unsigned short* Gh   = (unsigned short*)alloc((size_t)MPAD * 256 * 2);
  unsigned short* Gl   = (unsigned short*)alloc((size_t)MPAD * 256 * 2);
  unsigned short* P    = (unsigned short*)alloc((size_t)MPAD * 768 * 2);
  float*    Rroot = (float*)alloc((size_t)MPAD * 256 * 4);
  unsigned short* Hb = (unsigned short*)alloc((size_t)NN * 256 * 2);
  unsigned short* WTh[4];
  unsigned short* WTl[4];
  for (int i = 0; i < 4; ++i) {
    WTh[i] = (unsigned short*)alloc((size_t)1024 * 256 * 2);
    WTl[i] = (unsigned short*)alloc((size_t)1024 * 256 * 2);
  }
  float*    bns  = (float*)alloc(512 * 4);
  float*    dis  = (float*)alloc((size_t)NN * 4);
  int*      deg  = (int*)alloc((size_t)NN * 4);
  int*      rowp = (int*)alloc((size_t)(NN + 1) * 4);
  int*      cur  = (int*)alloc((size_t)NN * 4);
  int*      bsum = (int*)alloc(64 * 4);
  uintx2*   ed   = (uintx2*)alloc((size_t)NE * 8);

  hipMemsetAsync(deg, 0, (size_t)NN * 4, stream);
  hipMemsetAsync(cur, 0, (size_t)NN * 4, stream);
  k_deg<<<(NE + 255) / 256, 256, 0, stream>>>(dst, deg);
  k_dis<<<(NN + 255) / 256, 256, 0, stream>>>(deg, dis);
  k_scan1<<<SCAN_NB, SCAN_B, 0, stream>>>(deg, rowp, bsum);
  k_scan2<<<1, 64, 0, stream>>>(bsum);
  k_scan3<<<(NN + 255) / 256, 256, 0, stream>>>(rowp, bsum);
  k_build<<<(NE + 255) / 256, 256, 0, stream>>>(dst, srcp, etyp, dis, rowp, cur, ed);

  const int din_a[8]  = {128, 128, 256, 256, 256, 256, 256, 256};
  const int dout_a[8] = {128, 256, 256, 256, 256, 256, 256, 64};
  const int wi_a[8]   = {0, 1, 2, 2, 2, 2, 2, 3};
  const int gm = (MPAD + 255) / 256;   // 196

  // precompute all 4 weight sets (l2..l6 share wi=2)
  const int wdin[4]  = {128, 128, 256, 256};
  const int wdout[4] = {128, 256, 256, 64};
  for (int i = 0; i < 4; ++i)
    k_wcat2<<<(4 * wdout[i] * wdin[i] + 255) / 256, 256, 0, stream>>>(
        conv_r[i], conv_w[i], WTh[i], WTl[i], wdin[i], wdout[i]);

  for (int l = 0; l < 8; ++l) {
    const int din = din_a[l], dout = dout_a[l];
    const int wi = wi_a[l];

    if (l == 0)
      k_prep0<<<(NN * 32 + 255) / 256, 256, 0, stream>>>(x, emb, Gh, Gl);
    else
      k_prep<<<(NN * (din >> 3) + 255) / 256, 256, 0, stream>>>(
          Hb, bns, (l == 1) ? n1g : n2g, (l == 1) ? n1b : n2b, Gh, Gl, din);

    const int ny = 4 * dout / 128;
    if (din == 128)
      k_gemm4<4><<<gm * ny, 512, 0, stream>>>(Gh, Gl, WTh[wi], WTl[wi], Rroot, P, NN, dout, ny);
    else
      k_gemm4<8><<<gm * ny, 512, 0, stream>>>(Gh, Gl, WTh[wi], WTl[wi], Rroot, P, NN, dout, ny);

    if (l == 7) {
      k_agg2<8, true><<<(NN + 3) / 4, 256, 0, stream>>>(P, Rroot, conv_b[wi], rowp, ed, out);
    } else {
      if (dout == 256)
        k_agg2<32, false><<<(NN + 3) / 4, 256, 0, stream>>>(P, Rroot, conv_b[wi], rowp, ed, Hb);
      else
        k_agg2<16, false><<<(NN + 3) / 4, 256, 0, stream>>>(P, Rroot, conv_b[wi], rowp, ed, Hb);
      hipMemsetAsync(bns, 0, (size_t)2 * dout * 4, stream);
      k_bnstats<<<256, 256, 0, stream>>>(Hb, bns, dout);
    }
  }
}

// Round 17
// 1486.774 us; speedup vs baseline: 1.1704x; 1.1704x over previous
//
#include <hip/hip_runtime.h>

#define N_X  40000
#define NN   50000
#define NE   800000
#define MPAD 50048

using short8  = __attribute__((ext_vector_type(8))) short;
using floatx4 = __attribute__((ext_vector_type(4))) float;
using uintx2  = __attribute__((ext_vector_type(2))) unsigned int;
using uintx4  = __attribute__((ext_vector_type(4))) unsigned int;

typedef const __attribute__((address_space(1))) void gv_t;
typedef __attribute__((address_space(3))) void lv_t;

__device__ __forceinline__ unsigned short f2bf(float f) {
  unsigned u = __float_as_uint(f);
  u += 0x7FFF + ((u >> 16) & 1);           // RNE
  return (unsigned short)(u >> 16);
}
__device__ __forceinline__ float bf2f(unsigned v) {
  return __uint_as_float(v << 16);
}
__device__ __forceinline__ float h2f(unsigned v) {
  unsigned short s = (unsigned short)v;
  _Float16 f;
  __builtin_memcpy(&f, &s, 2);
  return (float)f;
}
__device__ __forceinline__ unsigned short f2h(float f) {
  _Float16 h = (_Float16)f;
  unsigned short s;
  __builtin_memcpy(&s, &h, 2);
  return s;
}

// ---------------- preprocessing ----------------
__global__ void k_deg(const int* __restrict__ dst, int* __restrict__ deg) {
  int e = blockIdx.x * blockDim.x + threadIdx.x;
  if (e < NE) atomicAdd(&deg[dst[e]], 1);
}

__global__ void k_dis(const int* __restrict__ deg, float* __restrict__ dis) {
  int i = blockIdx.x * blockDim.x + threadIdx.x;
  if (i < NN) dis[i] = deg[i] > 0 ? rsqrtf((float)deg[i]) : 0.f;
}

#define SCAN_B 1024
#define SCAN_NB 49
__global__ void k_scan1(const int* __restrict__ deg, int* __restrict__ rowp,
                        int* __restrict__ bsum) {
  __shared__ int buf[SCAN_B];
  int b = blockIdx.x;
  int i = b * SCAN_B + threadIdx.x;
  int v = (i < NN) ? deg[i] : 0;
  buf[threadIdx.x] = v;
  __syncthreads();
  for (int off = 1; off < SCAN_B; off <<= 1) {
    int t = (threadIdx.x >= off) ? buf[threadIdx.x - off] : 0;
    __syncthreads();
    buf[threadIdx.x] += t;
    __syncthreads();
  }
  if (i < NN) rowp[i] = buf[threadIdx.x] - v;   // block-local exclusive
  if (threadIdx.x == SCAN_B - 1) bsum[b] = buf[SCAN_B - 1];
}

__global__ void k_scan2(int* __restrict__ bsum) {
  if (threadIdx.x == 0) {
    int acc = 0;
    for (int i = 0; i < SCAN_NB; ++i) { int t = bsum[i]; bsum[i] = acc; acc += t; }
  }
}

__global__ void k_scan3(int* __restrict__ rowp, const int* __restrict__ bsum) {
  int i = blockIdx.x * blockDim.x + threadIdx.x;
  if (i < NN) rowp[i] += bsum[i >> 10];
  if (i == 0) rowp[NN] = NE;
}

__global__ void k_build(const int* __restrict__ dst, const int* __restrict__ src,
                        const int* __restrict__ typ, const float* __restrict__ dis,
                        const int* __restrict__ rowp, int* __restrict__ cur,
                        uintx2* __restrict__ ed) {
  int e = blockIdx.x * blockDim.x + threadIdx.x;
  if (e >= NE) return;
  int d = dst[e], s = src[e];
  int p = rowp[d] + atomicAdd(&cur[d], 1);
  uintx2 v;
  v.x = (unsigned)s | ((unsigned)typ[e] << 28);
  v.y = __float_as_uint(dis[d] * dis[s]);
  ed[p] = v;
}

// ---------------- per-layer kernels ----------------
// layer 0: concat(x, emb) -> Gh/Gl [NN][128]
__global__ void k_prep0(const float* __restrict__ x, const float* __restrict__ emb,
                        unsigned short* __restrict__ Gh, unsigned short* __restrict__ Gl) {
  int idx = blockIdx.x * blockDim.x + threadIdx.x;
  if (idx >= NN * 32) return;
  int r = idx >> 5;
  const float* srcp = (r < N_X) ? (x + (size_t)idx * 4)
                                : (emb + ((size_t)idx - (size_t)N_X * 32) * 4);
  float4 hv = *(const float4*)srcp;
  float vv[4] = {hv.x, hv.y, hv.z, hv.w};
  unsigned hw[2], lw[2];
#pragma unroll
  for (int q = 0; q < 2; ++q) {
    unsigned short h0 = f2bf(vv[2 * q]), h1 = f2bf(vv[2 * q + 1]);
    unsigned short l0 = f2bf(vv[2 * q] - bf2f(h0)), l1 = f2bf(vv[2 * q + 1] - bf2f(h1));
    hw[q] = (unsigned)h0 | ((unsigned)h1 << 16);
    lw[q] = (unsigned)l0 | ((unsigned)l1 << 16);
  }
  size_t o = (size_t)idx * 4;
  *(uintx2*)(Gh + o) = uintx2{hw[0], hw[1]};
  *(uintx2*)(Gl + o) = uintx2{lw[0], lw[1]};
}

// BN (inline scale/shift from raw sums) + ReLU: Hb bf16 [NN][din] -> Gh/Gl.
__global__ void k_prep(const unsigned short* __restrict__ Hb,
                       const float* __restrict__ bns, const float* __restrict__ g,
                       const float* __restrict__ b, unsigned short* __restrict__ Gh,
                       unsigned short* __restrict__ Gl, int din) {
  int idx = blockIdx.x * blockDim.x + threadIdx.x;
  if (idx >= NN * (din >> 3)) return;
  int c8 = (idx & ((din >> 3) - 1)) * 8;
  uintx4 hv = *(const uintx4*)(Hb + (size_t)idx * 8);
  unsigned hwv[4] = {hv.x, hv.y, hv.z, hv.w};
  unsigned hw[4], lw[4];
#pragma unroll
  for (int q = 0; q < 4; ++q) {
    unsigned short oo[2];
#pragma unroll
    for (int p = 0; p < 2; ++p) {
      int c = c8 + 2 * q + p;
      float mean = bns[c] * (1.f / NN);
      float var = bns[din + c] * (1.f / NN) - mean * mean;
      float rs = rsqrtf(var + 1e-5f);
      float sc = rs * g[c];
      float sh = b[c] - mean * sc;
      float v = bf2f((hwv[q] >> (16 * p)) & 0xFFFFu);
      v = fmaxf(v * sc + sh, 0.f);
      oo[p] = f2bf(v);
      float lo = v - bf2f(oo[p]);
      if (p == 0) lw[q] = (unsigned)f2bf(lo);
      else        lw[q] |= ((unsigned)f2bf(lo) << 16);
    }
    hw[q] = (unsigned)oo[0] | ((unsigned)oo[1] << 16);
  }
  size_t o = (size_t)idx * 8;
  *(uintx4*)(Gh + o) = uintx4{hw[0], hw[1], hw[2], hw[3]};
  *(uintx4*)(Gl + o) = uintx4{lw[0], lw[1], lw[2], lw[3]};
}

// Wc2T[n][k] hi/lo: n in [0,4*dout) columns of [root|W0|W1|W2], k in [0,din)
__global__ void k_wcat2(const float* __restrict__ root, const float* __restrict__ W,
                        unsigned short* __restrict__ BhT, unsigned short* __restrict__ BlT,
                        int din, int dout) {
  int idx = blockIdx.x * blockDim.x + threadIdx.x;
  if (idx >= 4 * dout * din) return;
  int n = idx / din, k = idx % din;
  float v;
  if (n < dout) v = root[(size_t)k * dout + n];
  else {
    int r = n / dout - 1, c = n % dout;
    v = W[((size_t)r * din + k) * dout + c];
  }
  unsigned short h = f2bf(v);
  BhT[idx] = h;
  BlT[idx] = f2bf(v - bf2f(h));
}

// ---------------- split-f32 MFMA GEMM (P-space, 256x64 tile) ----------------
// PROVEN R12/R13/R15 version: 115us at dout=256, MfmaUtil 29%, conflict-free.
__global__ __launch_bounds__(256, 2) void k_gemm2(
    const unsigned short* __restrict__ Ah, const unsigned short* __restrict__ Al,
    const unsigned short* __restrict__ Bh, const unsigned short* __restrict__ Bl,
    float* __restrict__ Rroot, unsigned short* __restrict__ P,
    int M, int K, int dout, int ny) {
  constexpr int TC = 40;               // 32 A chunks + 8 B chunks (1KB each)
  constexpr int CPW = 10;
  constexpr int NT = 2;
  __shared__ __align__(16) char lds[2][TC * 1024];

  const int tid = threadIdx.x;
  const int lane = tid & 63;
  const int w = tid >> 6;
  const int wm = w >> 1, wn = w & 1;
  const int r16 = lane & 15, kg = lane >> 4;

  // bijective XCD swizzle (m204); consecutive t share an A-panel (same bm)
  const int nwg = gridDim.x;
  const int q = nwg >> 3, r = nwg & 7;
  const int xcd = blockIdx.x & 7, pos = blockIdx.x >> 3;
  const int t = (xcd < r ? xcd * (q + 1) : r * (q + 1) + (xcd - r) * q) + pos;
  const int bm = (t / ny) * 256;
  const int bn = (t % ny) * 64;

  // coalesced per-lane staging source with XOR-swizzled seg
  const int rowseg = lane >> 2;
  const int seg = (lane & 3) ^ ((lane >> 3) & 3);
  const unsigned short* gb[CPW];
#pragma unroll
  for (int i = 0; i < CPW; ++i) {
    int c = w * CPW + i;
    const unsigned short* base;
    int row0;
    if (c < 16)      { base = Ah; row0 = bm + c * 16; }
    else if (c < 32) { base = Al; row0 = bm + (c - 16) * 16; }
    else if (c < 36) { base = Bh; row0 = bn + (c - 32) * 16; }
    else             { base = Bl; row0 = bn + (c - 36) * 16; }
    gb[i] = base + (size_t)(row0 + rowseg) * K + seg * 8;
  }

  floatx4 acc[8][NT];
#pragma unroll
  for (int i = 0; i < 8; ++i)
#pragma unroll
    for (int jj = 0; jj < NT; ++jj) acc[i][jj] = (floatx4)0.f;

  const int nk = K >> 5;

  auto stage = [&](int b, int tk) {
#pragma unroll
    for (int i = 0; i < CPW; ++i)
      __builtin_amdgcn_global_load_lds((gv_t*)(gb[i] + tk * 32),
                                       (lv_t*)&lds[b][(w * CPW + i) * 1024],
                                       16, 0, 0);
  };

  stage(0, 0);
  stage(1, 1);

  const int fo = r16 * 64 + ((kg ^ ((r16 >> 1) & 3)) * 16);

  int buf = 0;
  for (int tk = 0; tk < nk; ++tk) {
    if (tk < nk - 1) asm volatile("s_waitcnt vmcnt(10)" ::: "memory");
    else             asm volatile("s_waitcnt vmcnt(0)" ::: "memory");
    __builtin_amdgcn_s_barrier();

    const char* Lb = lds[buf];
    short8 bh[NT], bl[NT];
#pragma unroll
    for (int nt = 0; nt < NT; ++nt) {
      bh[nt] = *(const short8*)(Lb + (32 + wn * NT + nt) * 1024 + fo);
      bl[nt] = *(const short8*)(Lb + (36 + wn * NT + nt) * 1024 + fo);
    }

    __builtin_amdgcn_s_setprio(1);
#pragma unroll
    for (int mt = 0; mt < 8; ++mt) {
      short8 ah = *(const short8*)(Lb + (wm * 8 + mt) * 1024 + fo);
      short8 al = *(const short8*)(Lb + (16 + wm * 8 + mt) * 1024 + fo);
#pragma unroll
      for (int nt = 0; nt < NT; ++nt) {
        acc[mt][nt] = __builtin_amdgcn_mfma_f32_16x16x32_bf16(ah, bh[nt], acc[mt][nt], 0, 0, 0);
        acc[mt][nt] = __builtin_amdgcn_mfma_f32_16x16x32_bf16(ah, bl[nt], acc[mt][nt], 0, 0, 0);
        acc[mt][nt] = __builtin_amdgcn_mfma_f32_16x16x32_bf16(al, bh[nt], acc[mt][nt], 0, 0, 0);
      }
    }
    __builtin_amdgcn_s_setprio(0);

    __builtin_amdgcn_s_barrier();
    if (tk + 2 < nk) stage(buf, tk + 2);
    buf ^= 1;
  }

  // epilogue: D row = (lane>>4)*4 + reg, col = lane&15
  const int sec = bn / dout;           // block-uniform
  const int cb = bn - sec * dout;
#pragma unroll
  for (int mt = 0; mt < 8; ++mt) {
    const int gr0 = bm + wm * 128 + mt * 16 + kg * 4;
#pragma unroll
    for (int nt = 0; nt < NT; ++nt) {
      const int colL = cb + wn * 32 + nt * 16 + r16;
#pragma unroll
      for (int rr = 0; rr < 4; ++rr) {
        const int gr = gr0 + rr;
        if (gr >= M) continue;
        const float o = acc[mt][nt][rr];
        if (sec == 0) Rroot[(size_t)gr * dout + colL] = o;
        else          P[((size_t)gr * 3 + (sec - 1)) * dout + colL] = f2h(o);
      }
    }
  }
}

// P-space aggregation: ONE WAVE PER NODE (verified R12 structure).
// L lanes per edge, 8 f16 cols per lane. Output: bf16 H (l<7) or f32 (l==7).
template <int L, bool F32OUT>
__global__ void k_agg2(const unsigned short* __restrict__ P,
                       const float* __restrict__ Rroot,
                       const float* __restrict__ bias,
                       const int* __restrict__ rowp, const uintx2* __restrict__ ed,
                       void* __restrict__ OutV) {
  constexpr int G = 64 / L;
  constexpr int dout = L * 8;
  const int wid = (blockIdx.x * 256 + threadIdx.x) >> 6;
  if (wid >= NN) return;
  const int lane = threadIdx.x & 63;
  const int grp = lane / L;
  const int c0 = (lane & (L - 1)) * 8;
  const int beg = rowp[wid], end = rowp[wid + 1];
  float a[8] = {};
  for (int i = beg + grp; i < end; i += G) {
    const uintx2 e = ed[i];
    const float wv = __uint_as_float(e.y);
    const unsigned tt = e.x >> 28;
    const size_t off = ((size_t)(e.x & 0x0FFFFFFFu) * 3 + tt) * dout + c0;
    const uintx4 g = *(const uintx4*)(P + off);
    a[0] += wv * h2f(g.x & 0xFFFFu);
    a[1] += wv * h2f(g.x >> 16);
    a[2] += wv * h2f(g.y & 0xFFFFu);
    a[3] += wv * h2f(g.y >> 16);
    a[4] += wv * h2f(g.z & 0xFFFFu);
    a[5] += wv * h2f(g.z >> 16);
    a[6] += wv * h2f(g.w & 0xFFFFu);
    a[7] += wv * h2f(g.w >> 16);
  }
#pragma unroll
  for (int off = L; off < 64; off <<= 1) {
#pragma unroll
    for (int qq = 0; qq < 8; ++qq) a[qq] += __shfl_xor(a[qq], off);
  }
  if (grp == 0) {
    const size_t ob = (size_t)wid * dout + c0;
    const float4 bv0 = *(const float4*)(bias + c0);
    const float4 bv1 = *(const float4*)(bias + c0 + 4);
    const float4 rv0 = *(const float4*)(Rroot + ob);
    const float4 rv1 = *(const float4*)(Rroot + ob + 4);
    float o[8];
    o[0] = rv0.x + bv0.x + a[0];
    o[1] = rv0.y + bv0.y + a[1];
    o[2] = rv0.z + bv0.z + a[2];
    o[3] = rv0.w + bv0.w + a[3];
    o[4] = rv1.x + bv1.x + a[4];
    o[5] = rv1.y + bv1.y + a[5];
    o[6] = rv1.z + bv1.z + a[6];
    o[7] = rv1.w + bv1.w + a[7];
    if constexpr (F32OUT) {
      float* Out = (float*)OutV;
      *(float4*)(Out + ob) = make_float4(o[0], o[1], o[2], o[3]);
      *(float4*)(Out + ob + 4) = make_float4(o[4], o[5], o[6], o[7]);
    } else {
      unsigned short* Out = (unsigned short*)OutV;
      uintx4 pk;
      pk.x = (unsigned)f2bf(o[0]) | ((unsigned)f2bf(o[1]) << 16);
      pk.y = (unsigned)f2bf(o[2]) | ((unsigned)f2bf(o[3]) << 16);
      pk.z = (unsigned)f2bf(o[4]) | ((unsigned)f2bf(o[5]) << 16);
      pk.w = (unsigned)f2bf(o[6]) | ((unsigned)f2bf(o[7]) << 16);
      *(uintx4*)(Out + ob) = pk;
    }
  }
}

// ---------------- batch-norm stats (bf16 H, vectorized x8) ----------------
// thread owns 8 cols (16B uintx4 load); per-block LDS shared-atomic reduce;
// one global atomicAdd per col per block (256 blocks -> 131K global atomics).
__global__ void k_bnstats(const unsigned short* __restrict__ Hb,
                          float* __restrict__ sums, int d) {
  __shared__ float ls[512];            // [sum(0..255) | sumsq(256..511)]
  const int cg = d >> 3;               // col-groups of 8
  const int rpb = 256 / cg;            // rows in flight per block
  const int cgi = threadIdx.x & (cg - 1);
  const int rl = threadIdx.x / cg;
  const int c0 = cgi * 8;
  for (int i = threadIdx.x; i < 512; i += 256) ls[i] = 0.f;
  __syncthreads();

  float s[8] = {}, s2[8] = {};
  for (int row = blockIdx.x * rpb + rl; row < NN; row += gridDim.x * rpb) {
    uintx4 hv = *(const uintx4*)(Hb + (size_t)row * d + c0);
    unsigned wv[4] = {hv.x, hv.y, hv.z, hv.w};
#pragma unroll
    for (int q = 0; q < 4; ++q) {
      float v0 = bf2f(wv[q] & 0xFFFFu);
      float v1 = bf2f(wv[q] >> 16);
      s[2 * q] += v0;  s2[2 * q] += v0 * v0;
      s[2 * q + 1] += v1;  s2[2 * q + 1] += v1 * v1;
    }
  }
#pragma unroll
  for (int q = 0; q < 8; ++q) {
    atomicAdd(&ls[c0 + q], s[q]);
    atomicAdd(&ls[256 + c0 + q], s2[q]);
  }
  __syncthreads();
  if (threadIdx.x < d) {
    atomicAdd(&sums[threadIdx.x], ls[threadIdx.x]);
    atomicAdd(&sums[d + threadIdx.x], ls[256 + threadIdx.x]);
  }
}

// ---------------- host driver ----------------
extern "C" void kernel_launch(void* const* d_in, const int* in_sizes, int n_in,
                              void* d_out, int out_size, void* d_ws, size_t ws_size,
                              hipStream_t stream) {
  const float* x   = (const float*)d_in[0];
  const float* emb = (const float*)d_in[1];
  const float* conv_w[4] = {(const float*)d_in[2], (const float*)d_in[5],
                            (const float*)d_in[8], (const float*)d_in[11]};
  const float* conv_r[4] = {(const float*)d_in[3], (const float*)d_in[6],
                            (const float*)d_in[9], (const float*)d_in[12]};
  const float* conv_b[4] = {(const float*)d_in[4], (const float*)d_in[7],
                            (const float*)d_in[10], (const float*)d_in[13]};
  const float* n1g = (const float*)d_in[14];
  const float* n1b = (const float*)d_in[15];
  const float* n2g = (const float*)d_in[16];
  const float* n2b = (const float*)d_in[17];
  const int* eidx = (const int*)d_in[18];
  const int* etyp = (const int*)d_in[19];
  const int* dst  = eidx;
  const int* srcp = eidx + NE;
  float* out = (float*)d_out;

  char* w = (char*)d_ws;
  auto alloc = [&](size_t bytes) {
    char* p = w;
    w += (bytes + 255) & ~(size_t)255;
    return p;
  };
  unsigned short* Gh   = (unsigned short*)alloc((size_t)MPAD * 256 * 2);
  unsigned short* Gl   = (unsigned short*)alloc((size_t)MPAD * 256 * 2);
  unsigned short* P    = (unsigned short*)alloc((size_t)MPAD * 768 * 2);
  float*    Rroot = (float*)alloc((size_t)MPAD * 256 * 4);
  unsigned short* Hb = (unsigned short*)alloc((size_t)NN * 256 * 2);
  unsigned short* WTh[4];
  unsigned short* WTl[4];
  for (int i = 0; i < 4; ++i) {
    WTh[i] = (unsigned short*)alloc((size_t)1024 * 256 * 2);
    WTl[i] = (unsigned short*)alloc((size_t)1024 * 256 * 2);
  }
  float*    bns  = (float*)alloc(512 * 4);
  float*    dis  = (float*)alloc((size_t)NN * 4);
  int*      deg  = (int*)alloc((size_t)NN * 4);
  int*      rowp = (int*)alloc((size_t)(NN + 1) * 4);
  int*      cur  = (int*)alloc((size_t)NN * 4);
  int*      bsum = (int*)alloc(64 * 4);
  uintx2*   ed   = (uintx2*)alloc((size_t)NE * 8);

  hipMemsetAsync(deg, 0, (size_t)NN * 4, stream);
  hipMemsetAsync(cur, 0, (size_t)NN * 4, stream);
  k_deg<<<(NE + 255) / 256, 256, 0, stream>>>(dst, deg);
  k_dis<<<(NN + 255) / 256, 256, 0, stream>>>(deg, dis);
  k_scan1<<<SCAN_NB, SCAN_B, 0, stream>>>(deg, rowp, bsum);
  k_scan2<<<1, 64, 0, stream>>>(bsum);
  k_scan3<<<(NN + 255) / 256, 256, 0, stream>>>(rowp, bsum);
  k_build<<<(NE + 255) / 256, 256, 0, stream>>>(dst, srcp, etyp, dis, rowp, cur, ed);

  const int din_a[8]  = {128, 128, 256, 256, 256, 256, 256, 256};
  const int dout_a[8] = {128, 256, 256, 256, 256, 256, 256, 64};
  const int wi_a[8]   = {0, 1, 2, 2, 2, 2, 2, 3};
  const int gm = (MPAD + 255) / 256;   // 196

  // precompute all 4 weight sets (l2..l6 share wi=2)
  const int wdin[4]  = {128, 128, 256, 256};
  const int wdout[4] = {128, 256, 256, 64};
  for (int i = 0; i < 4; ++i)
    k_wcat2<<<(4 * wdout[i] * wdin[i] + 255) / 256, 256, 0, stream>>>(
        conv_r[i], conv_w[i], WTh[i], WTl[i], wdin[i], wdout[i]);

  for (int l = 0; l < 8; ++l) {
    const int din = din_a[l], dout = dout_a[l];
    const int wi = wi_a[l];

    if (l == 0)
      k_prep0<<<(NN * 32 + 255) / 256, 256, 0, stream>>>(x, emb, Gh, Gl);
    else
      k_prep<<<(NN * (din >> 3) + 255) / 256, 256, 0, stream>>>(
          Hb, bns, (l == 1) ? n1g : n2g, (l == 1) ? n1b : n2b, Gh, Gl, din);

    const int ny = 4 * dout / 64;
    k_gemm2<<<gm * ny, 256, 0, stream>>>(Gh, Gl, WTh[wi], WTl[wi], Rroot, P, NN, din, dout, ny);

    if (l == 7) {
      k_agg2<8, true><<<(NN + 3) / 4, 256, 0, stream>>>(P, Rroot, conv_b[wi], rowp, ed, out);
    } else {
      if (dout == 256)
        k_agg2<32, false><<<(NN + 3) / 4, 256, 0, stream>>>(P, Rroot, conv_b[wi], rowp, ed, Hb);
      else
        k_agg2<16, false><<<(NN + 3) / 4, 256, 0, stream>>>(P, Rroot, conv_b[wi], rowp, ed, Hb);
      hipMemsetAsync(bns, 0, (size_t)2 * dout * 4, stream);
      k_bnstats<<<256, 256, 0, stream>>>(Hb, bns, dout);
    }
  }
}